// Round 11
// baseline (70.282 us; speedup 1.0000x reference)
//
#include <hip/hip_runtime.h>

#define T 16
#define E 30
#define H 50
#define VOCAB 100
#define ROWS 208        // 13 row-tiles of 16; rows interleaved r = 4*unit + gate
#define K1 1.44269504089f   // log2(e)
#define K2 2.88539008178f   // 2*log2(e)

typedef _Float16 v8hf __attribute__((ext_vector_type(8)));
typedef float v4f __attribute__((ext_vector_type(4)));

extern "C" __device__ float __ocml_native_exp2_f32(float);
__device__ __forceinline__ float e2(float x)   { return __ocml_native_exp2_f32(x); }
__device__ __forceinline__ float rcpf(float x) { return __builtin_amdgcn_rcpf(x); }

// tbl[dir][v][r], r = 4*unit + gate (i,f,g,o), orig row = gate*50+unit.
// Rows pre-scaled: i/f/o by -log2e (sigmoid = rcp(1+exp2(x))), g by 2*log2e.
__global__ void build_tbl(const float* __restrict__ emb,
                          const float* __restrict__ w_ih,
                          const float* __restrict__ b_ih,
                          const float* __restrict__ b_hh,
                          float* __restrict__ tbl) {
    int idx = blockIdx.x * blockDim.x + threadIdx.x;
    if (idx >= VOCAB * ROWS) return;
    int v = idx / ROWS, r = idx % ROWS;
    float s = 0.f;
    if (r < 4 * H) {
        int orig = (r & 3) * H + (r >> 2);
        s = b_ih[orig] + b_hh[orig];
        const float* er = emb + v * E;
        const float* wr = w_ih + orig * E;
#pragma unroll
        for (int e = 0; e < E; ++e) s += er[e] * wr[e];
        s *= ((r & 3) == 2) ? K2 : -K1;
    }
    tbl[idx] = s;
}

// Block = 2 waves sharing one 16-seq group. Wave0: tiles 0-6 (units 0-27);
// wave1: tiles 7-12 (units 28-49). Both read full h; h double-buffered by
// step parity. Per-step sync = lgkmcnt(0) + RAW s_barrier (no vmcnt drain:
// tv prefetches stay in flight across the barrier).
// hbuf[buf][seg][lane][8] fp16: B-fragment = one conflict-free ds_read_b128.
template<int RT0, int NT>
__device__ __forceinline__ void run_tiles(
    const float* __restrict__ whh, const float* __restrict__ tb,
    const int* __restrict__ myids, _Float16* __restrict__ hb,
    float* __restrict__ out, int seq, int dir, int capt, int lane)
{
    const int l15 = lane & 15;
    const int lg = lane >> 4;

    // A-fragments (pre-scaled fp16 W) resident for the whole kernel.
    v8hf afrag[NT][2];
#pragma unroll
    for (int i = 0; i < NT; ++i) {
        const int r = (RT0 + i) * 16 + l15;
        const bool vr = (r < 4 * H);
        const int orig = vr ? ((r & 3) * H + (r >> 2)) : 0;
        const float sc = ((r & 3) == 2) ? K2 : -K1;
#pragma unroll
        for (int kh = 0; kh < 2; ++kh) {
            v8hf af;
#pragma unroll
            for (int j = 0; j < 8; ++j) {
                const int k = kh * 32 + lg * 8 + j;
                af[j] = (_Float16)((vr && k < H) ? sc * whh[orig * H + k] : 0.f);
            }
            afrag[i][kh] = af;
        }
    }

    // per-tile h write offsets (halves): u -> [u>>5][((u&31)>>3)*16+l15][u&7]
    unsigned wa[NT];
#pragma unroll
    for (int i = 0; i < NT; ++i) {
        const int u = (RT0 + i) * 4 + lg;
        wa[i] = ((u >> 5) << 9) + (((u & 31) >> 3) << 7) + (l15 << 3) + (u & 7);
    }

    float cs[NT];
#pragma unroll
    for (int i = 0; i < NT; ++i) cs[i] = 0.f;

    // prefetch tv for t=0
    v4f tv[NT];
    {
        const int id0 = myids[dir ? (T - 1) : 0];
        const float* __restrict__ trow = tb + id0 * ROWS;
#pragma unroll
        for (int i = 0; i < NT; ++i)
            tv[i] = *(const v4f*)(trow + (RT0 + i) * 16 + lg * 4);
    }

#pragma unroll 1
    for (int t = 0; t < T; ++t) {
        const int cur = t & 1, nxt = cur ^ 1;
        int tn = dir ? (T - 2 - t) : (t + 1);
        if (t == T - 1) tn = dir ? 0 : (T - 1);    // dummy valid index
        const int id_next = myids[tn];
        const float* __restrict__ trow_n = tb + id_next * ROWS;

        // full previous-step h (both segs), conflict-free b128 reads
        v8hf bh0 = *(const v8hf*)(hb + cur * 1024 + lane * 8);
        v8hf bh1 = *(const v8hf*)(hb + cur * 1024 + 512 + lane * 8);

        _Float16* wb = hb + nxt * 1024;
        const bool cap = (t == capt);

#pragma unroll
        for (int i = 0; i < NT; ++i) {
            v4f c = __builtin_amdgcn_mfma_f32_16x16x32_f16(afrag[i][0], bh0, tv[i], 0, 0, 0);
            c = __builtin_amdgcn_mfma_f32_16x16x32_f16(afrag[i][1], bh1, c, 0, 0, 0);
            tv[i] = *(const v4f*)(trow_n + (RT0 + i) * 16 + lg * 4);   // prefetch t+1

            // combined-denominator LSTM update: 5 exp2 + 2 rcp per unit
            float ei = e2(c[0]);
            float ef = e2(c[1]);
            float eg = e2(c[2]);
            float eo = e2(c[3]);
            float ai  = 1.f + ei;
            float bf  = 1.f + ef;
            float gp  = eg + 1.f;
            float gm2 = fmaf(K2, eg, -K2);           // K2*(eg-1)
            float num = fmaf(cs[i] * ai, gp, gm2 * bf);
            float rD  = rcpf(ai * bf * gp);
            float cn  = num * rD;                     // cs' = K2 * c_new
            cs[i] = cn;
            float ec  = e2(cn);                       // e^(2 c_new)
            float hn  = (ec - 1.f) * rcpf((1.f + eo) * (ec + 1.f));

            if (RT0 + i < 12 || lg < 2) {             // unit u < 50
                wb[wa[i]] = (_Float16)hn;
                if (cap) out[seq * 100 + dir * H + (RT0 + i) * 4 + lg] = hn;
            }
        }

        // drain only LDS ops, then raw barrier: tv prefetches stay in flight
        asm volatile("s_waitcnt lgkmcnt(0)" ::: "memory");
        __builtin_amdgcn_s_barrier();
        asm volatile("" ::: "memory");   // fence compiler reordering of ds ops
    }
}

__global__ __launch_bounds__(128, 4) void lstm_mfma(
    const int* __restrict__ ids,     // [NSEQ, T]
    const float* __restrict__ tbl,   // [2][VOCAB][ROWS]
    const float* __restrict__ whh_f, // [200][50]
    const float* __restrict__ whh_r, // [200][50]
    float* __restrict__ out)         // [NSEQ, 100]
{
    __shared__ _Float16 hbuf[2][2][64][8];   // 4 KB: [buf][seg][lane][8]

    const int tid = threadIdx.x;
    const int lane = tid & 63;
    const int wv = tid >> 6;
    const int l15 = lane & 15;
    const int b = blockIdx.x;
    const int dir = b >> 10;         // 2048 blocks: 0..1023 fwd, 1024..2047 rev
    const int seq = (b & 1023) * 16 + l15;

    const float* __restrict__ whh = dir ? whh_r : whh_f;
    const float* __restrict__ tb  = tbl + dir * (VOCAB * ROWS);
    const int* __restrict__ myids = ids + seq * T;

    // zero both h buffers (2048 halves = 1024 ints)
    {
        int* hz = (int*)&hbuf[0][0][0][0];
#pragma unroll
        for (int i = tid; i < 1024; i += 128) hz[i] = 0;
    }

    // ragged length -> capture step (per lane's own sequence)
    int capt;
    {
        const int4* q = (const int4*)myids;
        int4 a0 = q[0], a1 = q[1], a2 = q[2], a3 = q[3];
        int len = (a0.x != 0) + (a0.y != 0) + (a0.z != 0) + (a0.w != 0)
                + (a1.x != 0) + (a1.y != 0) + (a1.z != 0) + (a1.w != 0)
                + (a2.x != 0) + (a2.y != 0) + (a2.z != 0) + (a2.w != 0)
                + (a3.x != 0) + (a3.y != 0) + (a3.z != 0) + (a3.w != 0);
        capt = dir ? (T - 1) : ((len > 1) ? (len - 1) : 0);
    }

    __syncthreads();   // hbuf zeroed (full sync OK once, pre-loop)

    _Float16* hb = &hbuf[0][0][0][0];
    if (wv == 0) run_tiles<0, 7>(whh, tb, myids, hb, out, seq, dir, capt, lane);
    else         run_tiles<7, 6>(whh, tb, myids, hb, out, seq, dir, capt, lane);
}

extern "C" void kernel_launch(void* const* d_in, const int* in_sizes, int n_in,
                              void* d_out, int out_size, void* d_ws, size_t ws_size,
                              hipStream_t stream) {
    const int*   char_ids = (const int*)d_in[0];
    const float* emb      = (const float*)d_in[1];
    const float* w_ih_f   = (const float*)d_in[2];
    const float* w_hh_f   = (const float*)d_in[3];
    const float* b_ih_f   = (const float*)d_in[4];
    const float* b_hh_f   = (const float*)d_in[5];
    const float* w_ih_r   = (const float*)d_in[6];
    const float* w_hh_r   = (const float*)d_in[7];
    const float* b_ih_r   = (const float*)d_in[8];
    const float* b_hh_r   = (const float*)d_in[9];
    float* out = (float*)d_out;
    float* tbl = (float*)d_ws; // [2][VOCAB][ROWS] f32 = 166.4 KB

    const int nt = VOCAB * ROWS; // 20800
    build_tbl<<<(nt + 255) / 256, 256, 0, stream>>>(emb, w_ih_f, b_ih_f, b_hh_f, tbl);
    build_tbl<<<(nt + 255) / 256, 256, 0, stream>>>(emb, w_ih_r, b_ih_r, b_hh_r, tbl + nt);
    // 2048 blocks x 128 threads: one 16-seq group per block, 2 tile-split waves
    lstm_mfma<<<2048, 128, 0, stream>>>(char_ids, tbl, w_hh_f, w_hh_r, out);
}

// Round 12
// 66.101 us; speedup vs baseline: 1.0633x; 1.0633x over previous
//
#include <hip/hip_runtime.h>

#define T 16
#define E 30
#define H 50
#define VOCAB 100
#define ROWS 208        // 13 tiles of 16 rows
#define K1 1.44269504089f   // log2(e)
#define K2 2.88539008178f   // 2*log2(e)
#define NTILE 13

typedef _Float16 v8hf __attribute__((ext_vector_type(8)));
typedef float v4f __attribute__((ext_vector_type(4)));

extern "C" __device__ float __ocml_native_exp2_f32(float);
__device__ __forceinline__ float e2(float x)   { return __ocml_native_exp2_f32(x); }
__device__ __forceinline__ float rcpf(float x) { return __builtin_amdgcn_rcpf(x); }

// Lane-local unit assignment: tile i, row-group lgc, gate g  <->  unit u = lgc*13 + i.
// tbl row r = 16*tile + rho, rho = lgc*4 + gate. Pre-scaled by -log2e (i,f,o) / 2log2e (g).
__global__ void build_tbl(const float* __restrict__ emb,
                          const float* __restrict__ w_ih,
                          const float* __restrict__ b_ih,
                          const float* __restrict__ b_hh,
                          float* __restrict__ tbl) {
    int idx = blockIdx.x * blockDim.x + threadIdx.x;
    if (idx >= VOCAB * ROWS) return;
    int v = idx / ROWS, r = idx % ROWS;
    int tile = r >> 4, rho = r & 15;
    int lgc = rho >> 2, gate = rho & 3;
    int u = lgc * 13 + tile;
    float s = 0.f;
    if (u < H) {
        int orig = gate * H + u;
        s = b_ih[orig] + b_hh[orig];
        const float* er = emb + v * E;
        const float* wr = w_ih + orig * E;
#pragma unroll
        for (int e = 0; e < E; ++e) s += er[e] * wr[e];
        s *= (gate == 2) ? K2 : -K1;
    }
    tbl[idx] = s;
}

// Zero-LDS LSTM: wave owns 16 seqs; lane(lg,l15) produces h for units lg*13+i
// (i=0..12) as MFMA C-output AND consumes exactly those units as its own
// B-fragment next step. Recurrence is a pure register chain; no LDS/barriers.
__global__ __launch_bounds__(256, 2) void lstm_mfma(
    const int* __restrict__ ids,     // [NSEQ, T]
    const float* __restrict__ tbl,   // [2][VOCAB][ROWS]
    const float* __restrict__ whh_f, // [200][50]
    const float* __restrict__ whh_r, // [200][50]
    float* __restrict__ out)         // [NSEQ, 100]
{
    const int tid = threadIdx.x;
    const int lane = tid & 63;
    const int wave = tid >> 6;
    const int l15 = lane & 15;       // seq within wave / C col
    const int lg = lane >> 4;        // k-/B-slot group
    const int b = blockIdx.x;
    const int dir = b >> 8;          // 512 blocks: 0..255 fwd, 256..511 rev
    const int seq = (b & 255) * 64 + wave * 16 + l15;

    const float* __restrict__ whh = dir ? whh_r : whh_f;
    const float* __restrict__ tb  = tbl + dir * (VOCAB * ROWS);
    const int* __restrict__ myids = ids + seq * T;

    // ragged length -> capture step (per lane's own sequence)
    int capt;
    {
        const int4* q = (const int4*)myids;
        int4 a0 = q[0], a1 = q[1], a2 = q[2], a3 = q[3];
        int len = (a0.x != 0) + (a0.y != 0) + (a0.z != 0) + (a0.w != 0)
                + (a1.x != 0) + (a1.y != 0) + (a1.z != 0) + (a1.w != 0)
                + (a2.x != 0) + (a2.y != 0) + (a2.z != 0) + (a2.w != 0)
                + (a3.x != 0) + (a3.y != 0) + (a3.z != 0) + (a3.w != 0);
        capt = dir ? (T - 1) : ((len > 1) ? (len - 1) : 0);
    }

    // A-fragments: lane(lg,l15) tile i kh: af[j] = A[16i + l15][kh*32 + lg*8 + j]
    //   row 16i+l15: gate = l15&3 of unit urow = (l15>>2)*13 + i
    //   col k-slot (kh,lg,j): unit ucol = lg*13 + kh*8 + j  (pad if slot>=13 or >=50)
    const int gate = l15 & 3;
    const int rbase = (l15 >> 2) * 13;
    const float sc = (gate == 2) ? K2 : -K1;
    v8hf afrag[NTILE][2];
#pragma unroll
    for (int i = 0; i < NTILE; ++i) {
        const int urow = rbase + i;
        const bool vrow = (urow < H);
        const int worow = (gate * H + (vrow ? urow : 0)) * H;
#pragma unroll
        for (int kh = 0; kh < 2; ++kh) {
            v8hf af;
#pragma unroll
            for (int j = 0; j < 8; ++j) {
                const int m = kh * 8 + j;
                const int ucol = lg * 13 + m;
                const bool vcol = (m < NTILE) && (ucol < H);
                af[j] = (_Float16)((vrow && vcol) ? sc * whh[worow + ucol] : 0.f);
            }
            afrag[i][kh] = af;
        }
    }

    float cs[NTILE];
#pragma unroll
    for (int i = 0; i < NTILE; ++i) cs[i] = 0.f;

    v8hf b0 = (v8hf)(_Float16)0.f;   // h(t-1) units lg*13+0..7   (t=0: zeros)
    v8hf b1 = (v8hf)(_Float16)0.f;   // h(t-1) units lg*13+8..12 + pads

    // prefetch tv for t=0
    v4f tv[NTILE];
    {
        const int id0 = myids[dir ? (T - 1) : 0];
        const float* __restrict__ trow = tb + id0 * ROWS;
#pragma unroll
        for (int i = 0; i < NTILE; ++i)
            tv[i] = *(const v4f*)(trow + i * 16 + lg * 4);
    }

#pragma unroll 1   // rolled t-loop: ~4 KB body, I$-resident
    for (int t = 0; t < T; ++t) {
        int tn = dir ? (T - 2 - t) : (t + 1);
        if (t == T - 1) tn = dir ? 0 : (T - 1);    // dummy valid index
        const int id_next = myids[tn];
        const float* __restrict__ trow_n = tb + id_next * ROWS;
        const bool cap = (t == capt);

        float hn[NTILE];
#pragma unroll
        for (int i = 0; i < NTILE; ++i) {
            v4f c = __builtin_amdgcn_mfma_f32_16x16x32_f16(afrag[i][0], b0, tv[i], 0, 0, 0);
            c = __builtin_amdgcn_mfma_f32_16x16x32_f16(afrag[i][1], b1, c, 0, 0, 0);
            tv[i] = *(const v4f*)(trow_n + i * 16 + lg * 4);   // prefetch t+1

            // combined-denominator LSTM update: 5 exp2 + 2 rcp per unit
            float ei = e2(c[0]);
            float ef = e2(c[1]);
            float eg = e2(c[2]);
            float eo = e2(c[3]);
            float ai  = 1.f + ei;
            float bf  = 1.f + ef;
            float gp  = eg + 1.f;
            float gm2 = fmaf(K2, eg, -K2);            // K2*(eg-1)
            float num = fmaf(cs[i] * ai, gp, gm2 * bf);
            float rD  = rcpf(ai * bf * gp);
            float cn  = num * rD;                      // cs' = K2 * c_new
            cs[i] = cn;
            float ec  = e2(cn);                        // e^(2 c_new)
            float h   = (ec - 1.f) * rcpf((1.f + eo) * (ec + 1.f));

            if (i >= 11) h = (lg < 3) ? h : 0.f;       // pad units (lg3 i>=11)
            hn[i] = h;
            if (cap && (i < 11 || lg < 3))
                out[seq * 100 + dir * H + lg * NTILE + i] = h;
        }

        // pack h(t) into next-step B fragments (lane-local, no LDS)
        v8hf nb0, nb1;
#pragma unroll
        for (int j = 0; j < 8; ++j) nb0[j] = (_Float16)hn[j];
#pragma unroll
        for (int j = 0; j < 5; ++j) nb1[j] = (_Float16)hn[8 + j];
        nb1[5] = (_Float16)0.f; nb1[6] = (_Float16)0.f; nb1[7] = (_Float16)0.f;
        b0 = nb0; b1 = nb1;
    }
}

extern "C" void kernel_launch(void* const* d_in, const int* in_sizes, int n_in,
                              void* d_out, int out_size, void* d_ws, size_t ws_size,
                              hipStream_t stream) {
    const int*   char_ids = (const int*)d_in[0];
    const float* emb      = (const float*)d_in[1];
    const float* w_ih_f   = (const float*)d_in[2];
    const float* w_hh_f   = (const float*)d_in[3];
    const float* b_ih_f   = (const float*)d_in[4];
    const float* b_hh_f   = (const float*)d_in[5];
    const float* w_ih_r   = (const float*)d_in[6];
    const float* w_hh_r   = (const float*)d_in[7];
    const float* b_ih_r   = (const float*)d_in[8];
    const float* b_hh_r   = (const float*)d_in[9];
    float* out = (float*)d_out;
    float* tbl = (float*)d_ws; // [2][VOCAB][ROWS] f32 = 166.4 KB

    const int nt = VOCAB * ROWS; // 20800
    build_tbl<<<(nt + 255) / 256, 256, 0, stream>>>(emb, w_ih_f, b_ih_f, b_hh_f, tbl);
    build_tbl<<<(nt + 255) / 256, 256, 0, stream>>>(emb, w_ih_r, b_ih_r, b_hh_r, tbl + nt);
    // 512 blocks x 256: 4 fully independent 16-seq waves per block, zero LDS
    lstm_mfma<<<512, 256, 0, stream>>>(char_ids, tbl, w_hh_f, w_hh_r, out);
}